// Round 2
// baseline (244.835 us; speedup 1.0000x reference)
//
#include <hip/hip_runtime.h>

// FeedForwardQuantum, two-kernel split:
//   A: q = quantum(x @ w1^T + b1)      -- read-stream (134 MB in, 1 MB out)
//   B: out = q @ w2^T + b2             -- write-stream (1 MB in, 134 MB out)
// Quantum layer reduced analytically (Clifford circuit):
//   c_i = cos(h_i); q_f = parity-chain prefix products of c_i;
//   q7 = (even chain)*(odd chain).
// Rationale: fused version serialized read phase -> shuffle chain -> write
// phase inside every block (all pipes <30% busy, 83 us). Split kernels each
// have one latency class and enough TLP (8 blocks/CU) to hide it.

typedef float f4 __attribute__((ext_vector_type(4)));

constexpr int THREADS = 256;
constexpr int E       = 1024;
constexpr int R_TOTAL = 8 * 4096;     // 32768 rows

// ---- kernel A geometry ----
constexpr int TILE_A  = 16;           // rows/block -> 2048 blocks -> 8/CU
constexpr int RPI     = 4;            // rows per phase-1 iteration (ILP)
constexpr int NGROUP  = TILE_A / RPI;

// ---- kernel B geometry ----
constexpr int TILE_B  = 16;           // rows/block -> 2048 blocks -> 8/CU

// =====================  A: x -> q  =====================
__global__ __launch_bounds__(THREADS, 4)
void ffq_qcompute(const float* __restrict__ x,
                  const float* __restrict__ w1,
                  const float* __restrict__ b1,
                  float* __restrict__ qbuf,
                  const int qstride)
{
    __shared__ float part[TILE_A][33];          // stride 33: conflict-free
    __shared__ float b1s[8];

    const int t    = threadIdx.x;
    const int lane = t & 63;
    const int wid  = t >> 6;
    const int c0   = t * 4;                     // this thread's 4 columns of E

    if (t < 8) b1s[t] = b1[t];

    f4 w1r[8];
#pragma unroll
    for (int f = 0; f < 8; ++f)
        w1r[f] = *(const f4*)(w1 + f * E + c0);

    const int row0 = blockIdx.x * TILE_A;
    const float* xp = x + (size_t)row0 * E + c0;

    // phase 1: h partials + in-wave butterfly, 4 rows/iter (4 chains in
    // flight over the DS pipe, 4-8 loads in flight over VMEM).
    f4 cur[RPI];
#pragma unroll
    for (int r = 0; r < RPI; ++r)
        cur[r] = *(const f4*)(xp + (size_t)r * E);

#pragma unroll
    for (int g = 0; g < NGROUP; ++g) {
        f4 xc[RPI];
#pragma unroll
        for (int r = 0; r < RPI; ++r) xc[r] = cur[r];

        if (g + 1 < NGROUP) {
#pragma unroll
            for (int r = 0; r < RPI; ++r)
                cur[r] = *(const f4*)(xp + (size_t)((g + 1) * RPI + r) * E);
        }

        float h[RPI][8];
#pragma unroll
        for (int r = 0; r < RPI; ++r)
#pragma unroll
            for (int f = 0; f < 8; ++f)
                h[r][f] = xc[r].x * w1r[f].x + xc[r].y * w1r[f].y
                        + xc[r].z * w1r[f].z + xc[r].w * w1r[f].w;

        // multi-value butterfly: 8 sums across 64 lanes, 6 xor steps.
        // After step 3 lane L holds f = bitrev3(L&7); steps 4-6 all-reduce.
        {   const bool hb = lane & 1;
#pragma unroll
            for (int r = 0; r < RPI; ++r) {
                float s0 = hb ? h[r][0] : h[r][4];
                float s1 = hb ? h[r][1] : h[r][5];
                float s2 = hb ? h[r][2] : h[r][6];
                float s3 = hb ? h[r][3] : h[r][7];
                s0 = __shfl_xor(s0, 1); s1 = __shfl_xor(s1, 1);
                s2 = __shfl_xor(s2, 1); s3 = __shfl_xor(s3, 1);
                h[r][0] = (hb ? h[r][4] : h[r][0]) + s0;
                h[r][1] = (hb ? h[r][5] : h[r][1]) + s1;
                h[r][2] = (hb ? h[r][6] : h[r][2]) + s2;
                h[r][3] = (hb ? h[r][7] : h[r][3]) + s3;
            }
        }
        {   const bool hb = lane & 2;
#pragma unroll
            for (int r = 0; r < RPI; ++r) {
                float s0 = hb ? h[r][0] : h[r][2];
                float s1 = hb ? h[r][1] : h[r][3];
                s0 = __shfl_xor(s0, 2); s1 = __shfl_xor(s1, 2);
                h[r][0] = (hb ? h[r][2] : h[r][0]) + s0;
                h[r][1] = (hb ? h[r][3] : h[r][1]) + s1;
            }
        }
        float v[RPI];
        {   const bool hb = lane & 4;
#pragma unroll
            for (int r = 0; r < RPI; ++r) {
                float s0 = hb ? h[r][0] : h[r][1];
                s0 = __shfl_xor(s0, 4);
                v[r] = (hb ? h[r][1] : h[r][0]) + s0;
            }
        }
#pragma unroll
        for (int r = 0; r < RPI; ++r) v[r] += __shfl_xor(v[r], 8);
#pragma unroll
        for (int r = 0; r < RPI; ++r) v[r] += __shfl_xor(v[r], 16);
#pragma unroll
        for (int r = 0; r < RPI; ++r) v[r] += __shfl_xor(v[r], 32);

        if (lane < 8) {
            const int f = ((lane & 1) << 2) | (lane & 2) | ((lane >> 2) & 1);
#pragma unroll
            for (int r = 0; r < RPI; ++r)
                part[g * RPI + r][f * 4 + wid] = v[r];
        }
    }
    __syncthreads();

    // phase 2: q-finish + store (threads 0..127: 16 rows x 8 features)
    if (t < TILE_A * 8) {
        const int r = t >> 3;
        const int f = t & 7;
        const float hq = part[r][f * 4 + 0] + part[r][f * 4 + 1]
                       + part[r][f * 4 + 2] + part[r][f * 4 + 3] + b1s[f];
        float p = __cosf(hq);
        float u = __shfl_up(p, 2, 8); if (f >= 2) p *= u;
        u = __shfl_up(p, 4, 8);       if (f >= 4) p *= u;
        const float p6 = __shfl(p, 6, 8);   // even-chain full product
        if (f == 7) p *= p6;
        qbuf[(size_t)(row0 + r) * qstride + f] = p;
    }
}

// =====================  B: q -> out  =====================
__global__ __launch_bounds__(THREADS, 8)
void ffq_expand(const float* __restrict__ qbuf,
                const int qstride,
                const float* __restrict__ w2,
                const float* __restrict__ b2,
                float* __restrict__ out)
{
    __shared__ __align__(16) float qsh[TILE_B][8];

    const int t  = threadIdx.x;
    const int c0 = t * 4;
    const int row0 = blockIdx.x * TILE_B;

    // Stage q into LDS. In stash mode (qbuf aliases out) this is the
    // read-before-overwrite step; the barrier below orders it vs stores.
    if (t < TILE_B * 8)
        qsh[t >> 3][t & 7] = qbuf[(size_t)(row0 + (t >> 3)) * qstride + (t & 7)];

    float w2a[4][8];
#pragma unroll
    for (int j = 0; j < 4; ++j) {
        const f4 lo = *(const f4*)(w2 + (size_t)(c0 + j) * 8);
        const f4 hi = *(const f4*)(w2 + (size_t)(c0 + j) * 8 + 4);
        w2a[j][0] = lo.x; w2a[j][1] = lo.y; w2a[j][2] = lo.z; w2a[j][3] = lo.w;
        w2a[j][4] = hi.x; w2a[j][5] = hi.y; w2a[j][6] = hi.z; w2a[j][7] = hi.w;
    }
    const f4 b2v = *(const f4*)(b2 + c0);

    __syncthreads();

    // Pure store stream: per row 2 LDS broadcast reads + 32 FMA + 1 nt-store.
#pragma unroll
    for (int s = 0; s < TILE_B; ++s) {
        const f4 qlo = *(const f4*)(&qsh[s][0]);
        const f4 qhi = *(const f4*)(&qsh[s][4]);
        const float qv[8] = {qlo.x, qlo.y, qlo.z, qlo.w,
                             qhi.x, qhi.y, qhi.z, qhi.w};
        f4 o = b2v;
#pragma unroll
        for (int f = 0; f < 8; ++f) {
            o.x += qv[f] * w2a[0][f];
            o.y += qv[f] * w2a[1][f];
            o.z += qv[f] * w2a[2][f];
            o.w += qv[f] * w2a[3][f];
        }
        __builtin_nontemporal_store(o, (f4*)(out + (size_t)(row0 + s) * E + c0));
    }
}

extern "C" void kernel_launch(void* const* d_in, const int* in_sizes, int n_in,
                              void* d_out, int out_size, void* d_ws, size_t ws_size,
                              hipStream_t stream)
{
    const float* x  = (const float*)d_in[0];
    const float* w1 = (const float*)d_in[1];
    const float* b1 = (const float*)d_in[2];
    const float* w2 = (const float*)d_in[3];
    const float* b2 = (const float*)d_in[4];
    float* out = (float*)d_out;

    // q intermediate: 32768 x 8 f32 = 1 MB. Prefer workspace; else stash in
    // out[r][0..7] (kernel B reads it before overwriting, block-local).
    float* qbuf;
    int qstride;
    if (ws_size >= (size_t)R_TOTAL * 8 * sizeof(float)) {
        qbuf = (float*)d_ws; qstride = 8;
    } else {
        qbuf = out; qstride = E;
    }

    ffq_qcompute<<<dim3(R_TOTAL / TILE_A), THREADS, 0, stream>>>(x, w1, b1, qbuf, qstride);
    ffq_expand  <<<dim3(R_TOTAL / TILE_B), THREADS, 0, stream>>>(qbuf, qstride, w2, b2, out);
}

// Round 3
// 244.068 us; speedup vs baseline: 1.0031x; 1.0031x over previous
//
#include <hip/hip_runtime.h>

// FeedForwardQuantum fused, wave-autonomous:
//   out = q(x @ w1^T + b1) @ w2^T + b2
// Quantum layer reduced analytically (Clifford circuit):
//   c_i = cos(h_i); q_f = parity-chain prefix products of c_i;
//   q7 = (even chain)*(odd chain).
//
// Structure (round 3): ONE WAVE OWNS WHOLE ROWS. Lane L covers cols
// {k*256 + L*4 .. +3}, w1 fully register-resident (128 VGPR). Per row:
// 4 coalesced f4 loads -> 128 FMA -> ONE 10-shuffle butterfly (natural-f
// order) -> cos/prefix -> q in wave-private LDS. Then the wave reloads the
// same registers with w2 and streams out for its own rows. No cross-wave
// combine, no convoying barriers, 4x fewer DS ops than the 4-wave scheme.

typedef float f4 __attribute__((ext_vector_type(4)));

constexpr int THREADS = 64;          // one wave per block: fully independent
constexpr int PW      = 16;          // rows per wave
constexpr int E       = 1024;
constexpr int R_TOTAL = 8 * 4096;    // 32768 rows -> 2048 blocks -> 8 waves/CU

__global__ __launch_bounds__(THREADS, 2)   // cap 256 VGPR, 2 waves/SIMD
void ffq_kernel(const float* __restrict__ x,
                const float* __restrict__ w1,
                const float* __restrict__ b1,
                const float* __restrict__ w2,
                const float* __restrict__ b2,
                float* __restrict__ out)
{
    __shared__ __align__(16) float qsh[PW][8];

    const int L    = threadIdx.x;    // lane 0..63
    const int f    = L & 7;
    const int row0 = blockIdx.x * PW;

    // w1 register-resident: w1r[ff][k] = w1[ff][k*256 + L*4 .. +3]
    // (each load instruction covers a contiguous 1 KB: fully coalesced)
    f4 w1r[8][4];
#pragma unroll
    for (int ff = 0; ff < 8; ++ff)
#pragma unroll
        for (int k = 0; k < 4; ++k)
            w1r[ff][k] = *(const f4*)(w1 + ff * E + k * 256 + L * 4);

    const float b1v = b1[f];

    const float* xp = x + (size_t)row0 * E + L * 4;

    // ---------------- phase 1: rows -> q (wave-private) ----------------
    f4 cur[4];
#pragma unroll
    for (int k = 0; k < 4; ++k)
        cur[k] = *(const f4*)(xp + k * 256);

#pragma unroll
    for (int r = 0; r < PW; ++r) {
        f4 xc[4];
#pragma unroll
        for (int k = 0; k < 4; ++k) xc[k] = cur[k];

        // depth-2 pipeline: next row's loads in flight during this row's chain
        if (r + 1 < PW) {
#pragma unroll
            for (int k = 0; k < 4; ++k)
                cur[k] = *(const f4*)(xp + (size_t)(r + 1) * E + k * 256);
        }

        // h[ff] = partial dot over this lane's 16 columns (8 parallel chains)
        float h[8];
#pragma unroll
        for (int ff = 0; ff < 8; ++ff) {
            float s;
            s  = xc[0].x * w1r[ff][0].x + xc[0].y * w1r[ff][0].y
               + xc[0].z * w1r[ff][0].z + xc[0].w * w1r[ff][0].w;
            s += xc[1].x * w1r[ff][1].x + xc[1].y * w1r[ff][1].y
               + xc[1].z * w1r[ff][1].z + xc[1].w * w1r[ff][1].w;
            s += xc[2].x * w1r[ff][2].x + xc[2].y * w1r[ff][2].y
               + xc[2].z * w1r[ff][2].z + xc[2].w * w1r[ff][2].w;
            s += xc[3].x * w1r[ff][3].x + xc[3].y * w1r[ff][3].y
               + xc[3].z * w1r[ff][3].z + xc[3].w * w1r[ff][3].w;
            h[ff] = s;
        }

        // Butterfly in NATURAL f order: stage xor-1 pairs (0,1)(2,3)(4,5)(6,7)
        // selecting by L&1 -> after 3 merge stages lane L holds f = L&7;
        // stages 4-6 all-reduce across the remaining lane bits.
        {   const bool hb = L & 1;
            float s0 = hb ? h[0] : h[1];
            float s1 = hb ? h[2] : h[3];
            float s2 = hb ? h[4] : h[5];
            float s3 = hb ? h[6] : h[7];
            s0 = __shfl_xor(s0, 1); s1 = __shfl_xor(s1, 1);
            s2 = __shfl_xor(s2, 1); s3 = __shfl_xor(s3, 1);
            h[0] = (hb ? h[1] : h[0]) + s0;
            h[1] = (hb ? h[3] : h[2]) + s1;
            h[2] = (hb ? h[5] : h[4]) + s2;
            h[3] = (hb ? h[7] : h[6]) + s3;
        }
        {   const bool hb = L & 2;
            float s0 = hb ? h[0] : h[1];
            float s1 = hb ? h[2] : h[3];
            s0 = __shfl_xor(s0, 2); s1 = __shfl_xor(s1, 2);
            h[0] = (hb ? h[1] : h[0]) + s0;
            h[1] = (hb ? h[3] : h[2]) + s1;
        }
        float v;
        {   const bool hb = L & 4;
            float s0 = hb ? h[0] : h[1];
            s0 = __shfl_xor(s0, 4);
            v = (hb ? h[1] : h[0]) + s0;
        }
        v += __shfl_xor(v, 8);
        v += __shfl_xor(v, 16);
        v += __shfl_xor(v, 32);
        // every lane now holds the full h for feature f = L&7

        // q-finish: cos + segment prefix products (width-8, natural order)
        float p = __cosf(v + b1v);
        float u = __shfl_up(p, 2, 8); if (f >= 2) p *= u;
        u = __shfl_up(p, 4, 8);       if (f >= 4) p *= u;
        const float p6 = __shfl(p, 6, 8);   // even-chain full product
        if (f == 7) p *= p6;

        if (L < 8) qsh[r][L] = p;
    }

    __syncthreads();   // single-wave block: just orders LDS writes vs reads

    // ---------------- phase 2: q -> out (same wave, same rows) -------------
    // w2/b2 replace w1 in the same register space (w1r dead).
    float w2a[4][4][8];                 // [k][j][f]
#pragma unroll
    for (int k = 0; k < 4; ++k)
#pragma unroll
        for (int j = 0; j < 4; ++j) {
            const f4 lo = *(const f4*)(w2 + (size_t)(k * 256 + L * 4 + j) * 8);
            const f4 hi = *(const f4*)(w2 + (size_t)(k * 256 + L * 4 + j) * 8 + 4);
            w2a[k][j][0] = lo.x; w2a[k][j][1] = lo.y;
            w2a[k][j][2] = lo.z; w2a[k][j][3] = lo.w;
            w2a[k][j][4] = hi.x; w2a[k][j][5] = hi.y;
            w2a[k][j][6] = hi.z; w2a[k][j][7] = hi.w;
        }
    f4 b2r[4];
#pragma unroll
    for (int k = 0; k < 4; ++k)
        b2r[k] = *(const f4*)(b2 + k * 256 + L * 4);

#pragma unroll
    for (int r = 0; r < PW; ++r) {
        const f4 qlo = *(const f4*)(&qsh[r][0]);   // broadcast reads
        const f4 qhi = *(const f4*)(&qsh[r][4]);
        const float qv[8] = {qlo.x, qlo.y, qlo.z, qlo.w,
                             qhi.x, qhi.y, qhi.z, qhi.w};
#pragma unroll
        for (int k = 0; k < 4; ++k) {
            f4 o = b2r[k];
#pragma unroll
            for (int ff = 0; ff < 8; ++ff) {
                o.x += qv[ff] * w2a[k][0][ff];
                o.y += qv[ff] * w2a[k][1][ff];
                o.z += qv[ff] * w2a[k][2][ff];
                o.w += qv[ff] * w2a[k][3][ff];
            }
            __builtin_nontemporal_store(
                o, (f4*)(out + (size_t)(row0 + r) * E + k * 256 + L * 4));
        }
    }
}

extern "C" void kernel_launch(void* const* d_in, const int* in_sizes, int n_in,
                              void* d_out, int out_size, void* d_ws, size_t ws_size,
                              hipStream_t stream)
{
    const float* x  = (const float*)d_in[0];
    const float* w1 = (const float*)d_in[1];
    const float* b1 = (const float*)d_in[2];
    const float* w2 = (const float*)d_in[3];
    const float* b2 = (const float*)d_in[4];
    float* out = (float*)d_out;

    ffq_kernel<<<dim3(R_TOTAL / PW), THREADS, 0, stream>>>(x, w1, b1, w2, b2, out);
}

// Round 4
// 242.181 us; speedup vs baseline: 1.0110x; 1.0078x over previous
//
#include <hip/hip_runtime.h>

// FeedForwardQuantum fused: out = q(x@w1^T + b1) @ w2^T + b2
// Quantum layer reduced analytically (Clifford circuit):
//   c_i = cos(h_i); q_f = parity-chain prefix products of c_i;
//   q7 = (even chain)*(odd chain).
//
// Round 4: DS-free reduction critical path.
//   R0-R3 all stalled on a 13-op dependent DS-shuffle chain per row
//   (~120 cy/op). Here the cross-lane reduce uses VALU-pipe DPP only:
//     xor1, xor2 merges  -> quad_perm   (VALU)
//     bits {2,3} reduce  -> row_ror:4/8 (VALU)
//     bits {4,5} + cross-wave combine -> deferred to LDS partials,
//       written fire-and-forget (no consumer before the barrier).
//   Phase 2 sums 16 partials/(row,feature) from LDS, cos, width-8 prefix.
//   R0 skeleton kept: TILE=16, 256 thr, w1r[8] (32 VGPR - no respill).

typedef float f4 __attribute__((ext_vector_type(4)));

constexpr int THREADS = 256;
constexpr int TILE    = 16;          // rows per block -> 2048 blocks -> 8/CU
constexpr int E       = 1024;
constexpr int R_TOTAL = 8 * 4096;    // 32768 rows

template<int CTRL>
__device__ __forceinline__ float dppf(float v) {
    // update_dpp: old=0, row_mask=0xF, bank_mask=0xF, bound_ctrl=true.
    // All lanes active in phase 1, so no boundary zeros are observed.
    return __int_as_float(__builtin_amdgcn_update_dpp(
        0, __float_as_int(v), CTRL, 0xF, 0xF, true));
}
// DPP ctrl encodings (gfx9): quad_perm[1,0,3,2]=0xB1 (xor1),
// quad_perm[2,3,0,1]=0x4E (xor2), row_ror:4=0x124, row_ror:8=0x128.

__global__ __launch_bounds__(THREADS, 8)   // pin VGPR<=64: 8 waves/SIMD
void ffq_kernel(const float* __restrict__ x,
                const float* __restrict__ w1,
                const float* __restrict__ b1,
                const float* __restrict__ w2,
                const float* __restrict__ b2,
                float* __restrict__ out)
{
    // partials: [TILE][jj=0..15][9] (8 features + 1 pad word -> 4-way max
    // conflict on the phase-2 strided reads, conflict-free writes)
    __shared__ float part[TILE * 16 * 9];
    __shared__ __align__(16) float qsh[TILE][8];
    __shared__ float b1s[8];

    const int t    = threadIdx.x;
    const int lane = t & 63;
    const int wid  = t >> 6;
    const int c0   = t * 4;          // this thread's 4 columns of E

    if (t < 8) b1s[t] = b1[t];

    // w1 slice: w1[f][c0..c0+3] -> 32 VGPR (fits; no rematerialization)
    f4 w1r[8];
#pragma unroll
    for (int f = 0; f < 8; ++f)
        w1r[f] = *(const f4*)(w1 + f * E + c0);

    const int row0 = blockIdx.x * TILE;
    const float* xp = x + (size_t)row0 * E + c0;

    // LDS-writer bookkeeping: after ror4+ror8 every lane holds its
    // {bit2,bit3}-coset sum; lanes with (lane&12)==0 write the 4 per-wave
    // partials jj = wid*4 + (lane>>4), features lane&3 and (lane&3)+4.
    const bool writer = (lane & 12) == 0;
    const int  jj     = wid * 4 + (lane >> 4);   // 0..15
    const int  fb     = lane & 3;

    // ---------------- phase 1: h partials, DPP-only reduce ----------------
    f4 cur0 = *(const f4*)(xp);
    f4 cur1 = *(const f4*)(xp + E);

#pragma unroll
    for (int s = 0; s < TILE; ++s) {
        const f4 xc = cur0;
        cur0 = cur1;
        if (s + 2 < TILE)
            cur1 = *(const f4*)(xp + (size_t)(s + 2) * E);

        float h[8];
#pragma unroll
        for (int f = 0; f < 8; ++f)
            h[f] = xc.x * w1r[f].x + xc.y * w1r[f].y
                 + xc.z * w1r[f].z + xc.w * w1r[f].w;

        // merge xor1 (keep features with f&1 == lane&1)
        {
            const bool hb = lane & 1;
            float s0 = hb ? h[0] : h[1];
            float s1 = hb ? h[2] : h[3];
            float s2 = hb ? h[4] : h[5];
            float s3 = hb ? h[6] : h[7];
            s0 = dppf<0xB1>(s0); s1 = dppf<0xB1>(s1);
            s2 = dppf<0xB1>(s2); s3 = dppf<0xB1>(s3);
            h[0] = (hb ? h[1] : h[0]) + s0;   // feature 0+b0
            h[1] = (hb ? h[3] : h[2]) + s1;   // feature 2+b0
            h[2] = (hb ? h[5] : h[4]) + s2;   // feature 4+b0
            h[3] = (hb ? h[7] : h[6]) + s3;   // feature 6+b0
        }
        // merge xor2 (keep features with f&2 == lane&2)
        float v0, v1;
        {
            const bool hb = lane & 2;
            float s0 = hb ? h[0] : h[1];
            float s1 = hb ? h[2] : h[3];
            s0 = dppf<0x4E>(s0); s1 = dppf<0x4E>(s1);
            v0 = (hb ? h[1] : h[0]) + s0;     // feature lane&3
            v1 = (hb ? h[3] : h[2]) + s1;     // feature (lane&3)+4
        }
        // reduce lane bits {2,3}: rotate-reduce within 16-lane row (VALU)
        v0 += dppf<0x124>(v0);  v1 += dppf<0x124>(v1);   // row_ror:4
        v0 += dppf<0x128>(v0);  v1 += dppf<0x128>(v1);   // row_ror:8

        // defer bits {4,5} + cross-wave: fire-and-forget LDS partials
        if (writer) {
            const int w = (s * 16 + jj) * 9 + fb;
            part[w]     = v0;
            part[w + 4] = v1;
        }
    }
    __syncthreads();   // barrier 1 of 2

    // ------------- phase 2: sum partials, cos, prefix (t<128) -------------
    if (t < TILE * 8) {
        const int r = t >> 3;
        const int f = t & 7;
        float hq = b1s[f];
#pragma unroll
        for (int j = 0; j < 16; ++j)
            hq += part[(r * 16 + j) * 9 + f];
        float p = __cosf(hq);
        float u = __shfl_up(p, 2, 8); if (f >= 2) p *= u;
        u = __shfl_up(p, 4, 8);       if (f >= 4) p *= u;
        const float p6 = __shfl(p, 6, 8);   // even-chain full product
        if (f == 7) p *= p6;
        qsh[r][f] = p;
    }

    // w2/b2 register loads: latency overlaps phase 2 + barrier; w1r dead.
    float w2a[4][8];
#pragma unroll
    for (int j = 0; j < 4; ++j) {
        const f4 lo = *(const f4*)(w2 + (size_t)(c0 + j) * 8);
        const f4 hi = *(const f4*)(w2 + (size_t)(c0 + j) * 8 + 4);
        w2a[j][0] = lo.x; w2a[j][1] = lo.y; w2a[j][2] = lo.z; w2a[j][3] = lo.w;
        w2a[j][4] = hi.x; w2a[j][5] = hi.y; w2a[j][6] = hi.z; w2a[j][7] = hi.w;
    }
    const f4 b2v = *(const f4*)(b2 + c0);

    __syncthreads();   // barrier 2 of 2

    // ---------------- phase 3: out = q @ w2^T + b2 ----------------
#pragma unroll
    for (int s = 0; s < TILE; ++s) {
        const f4 qlo = *(const f4*)(&qsh[s][0]);   // broadcast reads
        const f4 qhi = *(const f4*)(&qsh[s][4]);
        const float qv[8] = {qlo.x, qlo.y, qlo.z, qlo.w,
                             qhi.x, qhi.y, qhi.z, qhi.w};
        f4 o = b2v;
#pragma unroll
        for (int f = 0; f < 8; ++f) {
            o.x += qv[f] * w2a[0][f];
            o.y += qv[f] * w2a[1][f];
            o.z += qv[f] * w2a[2][f];
            o.w += qv[f] * w2a[3][f];
        }
        __builtin_nontemporal_store(o, (f4*)(out + (size_t)(row0 + s) * E + c0));
    }
}

extern "C" void kernel_launch(void* const* d_in, const int* in_sizes, int n_in,
                              void* d_out, int out_size, void* d_ws, size_t ws_size,
                              hipStream_t stream)
{
    const float* x  = (const float*)d_in[0];
    const float* w1 = (const float*)d_in[1];
    const float* b1 = (const float*)d_in[2];
    const float* w2 = (const float*)d_in[3];
    const float* b2 = (const float*)d_in[4];
    float* out = (float*)d_out;

    ffq_kernel<<<dim3(R_TOTAL / TILE), THREADS, 0, stream>>>(x, w1, b1, w2, b2, out);
}

// Round 5
// 241.849 us; speedup vs baseline: 1.0123x; 1.0014x over previous
//
#include <hip/hip_runtime.h>

// FeedForwardQuantum fused: out = q(x@w1^T + b1) @ w2^T + b2
// Quantum layer reduced analytically (Clifford circuit):
//   c_i = cos(h_i); q_f = parity-chain prefix products of c_i;
//   q7 = (even chain)*(odd chain).
//
// Round 5: deep ring prefetch.
//   R0-R4 (five structures) all pinned at 84-88us with every pipe <30%
//   busy. Common factor: <=2 outstanding loads per wave, with compute
//   between consume and next issue -> convoyed issue gaps starve the
//   memory system (the harness fill kernel sustains 6.7 TB/s on this
//   chip; we see 2.35). This round keeps R4's verified DPP-reduce
//   skeleton and changes ONLY the memory engine: depth-6 ring prefetch
//   (6 KB/wave in flight) + launch_bounds(256,6) so the ring + w1 slice
//   stay register-resident without rematerialization (R3 lesson).

typedef float f4 __attribute__((ext_vector_type(4)));

constexpr int THREADS = 256;
constexpr int TILE    = 16;          // rows per block -> 2048 blocks
constexpr int DEPTH   = 6;           // prefetch ring depth (rows in flight)
constexpr int E       = 1024;
constexpr int R_TOTAL = 8 * 4096;    // 32768 rows

template<int CTRL>
__device__ __forceinline__ float dppf(float v) {
    // update_dpp: old=0, row_mask=0xF, bank_mask=0xF, bound_ctrl=true.
    // All lanes active in phase 1, so no boundary zeros are observed.
    return __int_as_float(__builtin_amdgcn_update_dpp(
        0, __float_as_int(v), CTRL, 0xF, 0xF, true));
}
// DPP ctrl encodings (gfx9): quad_perm[1,0,3,2]=0xB1 (xor1),
// quad_perm[2,3,0,1]=0x4E (xor2), row_ror:4=0x124, row_ror:8=0x128.

__global__ __launch_bounds__(THREADS, 6)   // VGPR cap ~85: ring(24)+w1r(32)
void ffq_kernel(const float* __restrict__ x,
                const float* __restrict__ w1,
                const float* __restrict__ b1,
                const float* __restrict__ w2,
                const float* __restrict__ b2,
                float* __restrict__ out)
{
    // partials: [TILE][jj=0..15][9] (8 features + 1 pad word)
    __shared__ float part[TILE * 16 * 9];
    __shared__ __align__(16) float qsh[TILE][8];
    __shared__ float b1s[8];

    const int t    = threadIdx.x;
    const int lane = t & 63;
    const int wid  = t >> 6;
    const int c0   = t * 4;          // this thread's 4 columns of E

    if (t < 8) b1s[t] = b1[t];

    // w1 slice: w1[f][c0..c0+3] -> 32 VGPR
    f4 w1r[8];
#pragma unroll
    for (int f = 0; f < 8; ++f)
        w1r[f] = *(const f4*)(w1 + f * E + c0);

    const int row0 = blockIdx.x * TILE;
    const float* xp = x + (size_t)row0 * E + c0;

    // LDS-writer bookkeeping: after ror4+ror8 every lane holds its
    // {bit2,bit3}-coset sum; lanes with (lane&12)==0 write the 4 per-wave
    // partials jj = wid*4 + (lane>>4), features lane&3 and (lane&3)+4.
    const bool writer = (lane & 12) == 0;
    const int  jj     = wid * 4 + (lane >> 4);   // 0..15
    const int  fb     = lane & 3;

    // ---------------- phase 1: h partials, DPP-only reduce ----------------
    // Depth-6 ring: 6 independent loads in flight per thread at all times.
    // Slot s%DEPTH is consumed at iteration s and immediately reloaded with
    // row s+DEPTH; full unroll keeps all ring indices compile-time constant.
    f4 ring[DEPTH];
#pragma unroll
    for (int d = 0; d < DEPTH; ++d)
        ring[d] = *(const f4*)(xp + (size_t)d * E);

#pragma unroll
    for (int s = 0; s < TILE; ++s) {
        const f4 xc = ring[s % DEPTH];
        if (s + DEPTH < TILE)
            ring[s % DEPTH] = *(const f4*)(xp + (size_t)(s + DEPTH) * E);

        float h[8];
#pragma unroll
        for (int f = 0; f < 8; ++f)
            h[f] = xc.x * w1r[f].x + xc.y * w1r[f].y
                 + xc.z * w1r[f].z + xc.w * w1r[f].w;

        // merge xor1 (keep features with f&1 == lane&1)
        {
            const bool hb = lane & 1;
            float s0 = hb ? h[0] : h[1];
            float s1 = hb ? h[2] : h[3];
            float s2 = hb ? h[4] : h[5];
            float s3 = hb ? h[6] : h[7];
            s0 = dppf<0xB1>(s0); s1 = dppf<0xB1>(s1);
            s2 = dppf<0xB1>(s2); s3 = dppf<0xB1>(s3);
            h[0] = (hb ? h[1] : h[0]) + s0;   // feature 0+b0
            h[1] = (hb ? h[3] : h[2]) + s1;   // feature 2+b0
            h[2] = (hb ? h[5] : h[4]) + s2;   // feature 4+b0
            h[3] = (hb ? h[7] : h[6]) + s3;   // feature 6+b0
        }
        // merge xor2 (keep features with f&2 == lane&2)
        float v0, v1;
        {
            const bool hb = lane & 2;
            float s0 = hb ? h[0] : h[1];
            float s1 = hb ? h[2] : h[3];
            s0 = dppf<0x4E>(s0); s1 = dppf<0x4E>(s1);
            v0 = (hb ? h[1] : h[0]) + s0;     // feature lane&3
            v1 = (hb ? h[3] : h[2]) + s1;     // feature (lane&3)+4
        }
        // reduce lane bits {2,3}: rotate-reduce within 16-lane row (VALU)
        v0 += dppf<0x124>(v0);  v1 += dppf<0x124>(v1);   // row_ror:4
        v0 += dppf<0x128>(v0);  v1 += dppf<0x128>(v1);   // row_ror:8

        // defer bits {4,5} + cross-wave: fire-and-forget LDS partials
        if (writer) {
            const int w = (s * 16 + jj) * 9 + fb;
            part[w]     = v0;
            part[w + 4] = v1;
        }
    }
    __syncthreads();   // barrier 1 of 2

    // ------------- phase 2: sum partials, cos, prefix (t<128) -------------
    if (t < TILE * 8) {
        const int r = t >> 3;
        const int f = t & 7;
        float hq = b1s[f];
#pragma unroll
        for (int j = 0; j < 16; ++j)
            hq += part[(r * 16 + j) * 9 + f];
        float p = __cosf(hq);
        float u = __shfl_up(p, 2, 8); if (f >= 2) p *= u;
        u = __shfl_up(p, 4, 8);       if (f >= 4) p *= u;
        const float p6 = __shfl(p, 6, 8);   // even-chain full product
        if (f == 7) p *= p6;
        qsh[r][f] = p;
    }

    // w2/b2 register loads: latency overlaps phase 2 + barrier; w1r dead.
    float w2a[4][8];
#pragma unroll
    for (int j = 0; j < 4; ++j) {
        const f4 lo = *(const f4*)(w2 + (size_t)(c0 + j) * 8);
        const f4 hi = *(const f4*)(w2 + (size_t)(c0 + j) * 8 + 4);
        w2a[j][0] = lo.x; w2a[j][1] = lo.y; w2a[j][2] = lo.z; w2a[j][3] = lo.w;
        w2a[j][4] = hi.x; w2a[j][5] = hi.y; w2a[j][6] = hi.z; w2a[j][7] = hi.w;
    }
    const f4 b2v = *(const f4*)(b2 + c0);

    __syncthreads();   // barrier 2 of 2

    // ---------------- phase 3: out = q @ w2^T + b2 ----------------
#pragma unroll
    for (int s = 0; s < TILE; ++s) {
        const f4 qlo = *(const f4*)(&qsh[s][0]);   // broadcast reads
        const f4 qhi = *(const f4*)(&qsh[s][4]);
        const float qv[8] = {qlo.x, qlo.y, qlo.z, qlo.w,
                             qhi.x, qhi.y, qhi.z, qhi.w};
        f4 o = b2v;
#pragma unroll
        for (int f = 0; f < 8; ++f) {
            o.x += qv[f] * w2a[0][f];
            o.y += qv[f] * w2a[1][f];
            o.z += qv[f] * w2a[2][f];
            o.w += qv[f] * w2a[3][f];
        }
        __builtin_nontemporal_store(o, (f4*)(out + (size_t)(row0 + s) * E + c0));
    }
}

extern "C" void kernel_launch(void* const* d_in, const int* in_sizes, int n_in,
                              void* d_out, int out_size, void* d_ws, size_t ws_size,
                              hipStream_t stream)
{
    const float* x  = (const float*)d_in[0];
    const float* w1 = (const float*)d_in[1];
    const float* b1 = (const float*)d_in[2];
    const float* w2 = (const float*)d_in[3];
    const float* b2 = (const float*)d_in[4];
    float* out = (float*)d_out;

    ffq_kernel<<<dim3(R_TOTAL / TILE), THREADS, 0, stream>>>(x, w1, b1, w2, b2, out);
}

// Round 6
// 241.130 us; speedup vs baseline: 1.0154x; 1.0030x over previous
//
#include <hip/hip_runtime.h>

// FeedForwardQuantum fused: out = q(x@w1^T + b1) @ w2^T + b2
// Quantum layer reduced analytically (Clifford circuit):
//   c_i = cos(h_i); q_f = parity-chain prefix products of c_i;
//   q7 = (even chain)*(odd chain).
//
// Round 6: async global_load_lds staging of x.
//   R0-R5: every variant loading x into VGPRs was re-scheduled by the
//   compiler into a <=2-deep pipeline (R5's depth-6 ring compiled to
//   VGPR_Count=40 -> ring collapsed). Reads run at 2.3 TB/s while the
//   harness fill writes at 6.7 TB/s: exposed read latency, too few
//   outstanding reads. global_load_lds is fire-and-forget DMA with no
//   VGPR destination - the compiler cannot sink or collapse it. Each
//   wave bursts 8 stages (8 KB in flight), waits once, then computes
//   from LDS. Compute phases (DPP butterfly, partials, q-finish,
//   expand) are bit-identical to the verified R4 kernel.

typedef float f4 __attribute__((ext_vector_type(4)));

constexpr int THREADS = 256;
constexpr int TILE    = 8;           // rows per block -> 4096 blocks
constexpr int E       = 1024;
constexpr int R_TOTAL = 8 * 4096;    // 32768 rows

template<int CTRL>
__device__ __forceinline__ float dppf(float v) {
    // update_dpp: old=0, row_mask=0xF, bank_mask=0xF, bound_ctrl=true.
    // All lanes active in phase 1, so no boundary zeros are observed.
    return __int_as_float(__builtin_amdgcn_update_dpp(
        0, __float_as_int(v), CTRL, 0xF, 0xF, true));
}
// DPP ctrl encodings (gfx9): quad_perm[1,0,3,2]=0xB1 (xor1),
// quad_perm[2,3,0,1]=0x4E (xor2), row_ror:4=0x124, row_ror:8=0x128.

__global__ __launch_bounds__(THREADS, 4)
void ffq_kernel(const float* __restrict__ x,
                const float* __restrict__ w1,
                const float* __restrict__ b1,
                const float* __restrict__ w2,
                const float* __restrict__ b2,
                float* __restrict__ out)
{
    // x stage: [TILE][1024] floats, linear (global_load_lds needs a
    // contiguous wave-uniform-base + lane*16B destination). 32 KB.
    __shared__ __align__(16) float lds_x[TILE * E];
    // partials: [TILE][jj=0..15][9] (8 features + 1 pad word)
    __shared__ float part[TILE * 16 * 9];
    __shared__ __align__(16) float qsh[TILE][8];
    __shared__ float b1s[8];

    const int t    = threadIdx.x;
    const int lane = t & 63;
    const int wid  = t >> 6;
    const int c0   = t * 4;          // this thread's 4 columns of E

    const int row0 = blockIdx.x * TILE;

    // ---- stage burst: 8 fire-and-forget DMA loads, 8 KB/wave in flight ----
    // Wave wid stages its quarter of each row: LDS dest is wave-uniform
    // (&lds_x[r*E + wid*256]); HW adds lane*16B. Global src is per-lane.
#pragma unroll
    for (int r = 0; r < TILE; ++r) {
        __builtin_amdgcn_global_load_lds(
            (const __attribute__((address_space(1))) void*)
                (x + (size_t)(row0 + r) * E + wid * 256 + lane * 4),
            (__attribute__((address_space(3))) void*)
                (&lds_x[r * E + wid * 256]),
            16, 0, 0);
    }

    // Register loads issued while the DMA burst is in flight.
    if (t < 8) b1s[t] = b1[t];
    f4 w1r[8];
#pragma unroll
    for (int f = 0; f < 8; ++f)
        w1r[f] = *(const f4*)(w1 + f * E + c0);

    // LDS-writer bookkeeping: after ror4+ror8 every lane holds its
    // {bit2,bit3}-coset sum; lanes with (lane&12)==0 write the 4 per-wave
    // partials jj = wid*4 + (lane>>4), features lane&3 and (lane&3)+4.
    const bool writer = (lane & 12) == 0;
    const int  jj     = wid * 4 + (lane >> 4);   // 0..15
    const int  fb     = lane & 3;

    // Drain the DMA burst (also covers w1r). Each wave consumes only the
    // LDS bytes it staged itself -> no barrier needed before phase 1.
    asm volatile("s_waitcnt vmcnt(0)" ::: "memory");

    // ---------------- phase 1: h partials, DPP-only reduce ----------------
#pragma unroll
    for (int s = 0; s < TILE; ++s) {
        const f4 xc = *(const f4*)(&lds_x[s * E + t * 4]);  // ds_read_b128

        float h[8];
#pragma unroll
        for (int f = 0; f < 8; ++f)
            h[f] = xc.x * w1r[f].x + xc.y * w1r[f].y
                 + xc.z * w1r[f].z + xc.w * w1r[f].w;

        // merge xor1 (keep features with f&1 == lane&1)
        {
            const bool hb = lane & 1;
            float s0 = hb ? h[0] : h[1];
            float s1 = hb ? h[2] : h[3];
            float s2 = hb ? h[4] : h[5];
            float s3 = hb ? h[6] : h[7];
            s0 = dppf<0xB1>(s0); s1 = dppf<0xB1>(s1);
            s2 = dppf<0xB1>(s2); s3 = dppf<0xB1>(s3);
            h[0] = (hb ? h[1] : h[0]) + s0;   // feature 0+b0
            h[1] = (hb ? h[3] : h[2]) + s1;   // feature 2+b0
            h[2] = (hb ? h[5] : h[4]) + s2;   // feature 4+b0
            h[3] = (hb ? h[7] : h[6]) + s3;   // feature 6+b0
        }
        // merge xor2 (keep features with f&2 == lane&2)
        float v0, v1;
        {
            const bool hb = lane & 2;
            float s0 = hb ? h[0] : h[1];
            float s1 = hb ? h[2] : h[3];
            s0 = dppf<0x4E>(s0); s1 = dppf<0x4E>(s1);
            v0 = (hb ? h[1] : h[0]) + s0;     // feature lane&3
            v1 = (hb ? h[3] : h[2]) + s1;     // feature (lane&3)+4
        }
        // reduce lane bits {2,3}: rotate-reduce within 16-lane row (VALU)
        v0 += dppf<0x124>(v0);  v1 += dppf<0x124>(v1);   // row_ror:4
        v0 += dppf<0x128>(v0);  v1 += dppf<0x128>(v1);   // row_ror:8

        // defer bits {4,5} + cross-wave: fire-and-forget LDS partials
        if (writer) {
            const int w = (s * 16 + jj) * 9 + fb;
            part[w]     = v0;
            part[w + 4] = v1;
        }
    }
    __syncthreads();   // barrier 1 of 2

    // ------------- phase 2: sum partials, cos, prefix (t<64) -------------
    if (t < TILE * 8) {
        const int r = t >> 3;
        const int f = t & 7;
        float hq = b1s[f];
#pragma unroll
        for (int j = 0; j < 16; ++j)
            hq += part[(r * 16 + j) * 9 + f];
        float p = __cosf(hq);
        float u = __shfl_up(p, 2, 8); if (f >= 2) p *= u;
        u = __shfl_up(p, 4, 8);       if (f >= 4) p *= u;
        const float p6 = __shfl(p, 6, 8);   // even-chain full product
        if (f == 7) p *= p6;
        qsh[r][f] = p;
    }

    // w2/b2 register loads: latency overlaps phase 2 + barrier; w1r dead.
    float w2a[4][8];
#pragma unroll
    for (int j = 0; j < 4; ++j) {
        const f4 lo = *(const f4*)(w2 + (size_t)(c0 + j) * 8);
        const f4 hi = *(const f4*)(w2 + (size_t)(c0 + j) * 8 + 4);
        w2a[j][0] = lo.x; w2a[j][1] = lo.y; w2a[j][2] = lo.z; w2a[j][3] = lo.w;
        w2a[j][4] = hi.x; w2a[j][5] = hi.y; w2a[j][6] = hi.z; w2a[j][7] = hi.w;
    }
    const f4 b2v = *(const f4*)(b2 + c0);

    __syncthreads();   // barrier 2 of 2

    // ---------------- phase 3: out = q @ w2^T + b2 ----------------
#pragma unroll
    for (int s = 0; s < TILE; ++s) {
        const f4 qlo = *(const f4*)(&qsh[s][0]);   // broadcast reads
        const f4 qhi = *(const f4*)(&qsh[s][4]);
        const float qv[8] = {qlo.x, qlo.y, qlo.z, qlo.w,
                             qhi.x, qhi.y, qhi.z, qhi.w};
        f4 o = b2v;
#pragma unroll
        for (int f = 0; f < 8; ++f) {
            o.x += qv[f] * w2a[0][f];
            o.y += qv[f] * w2a[1][f];
            o.z += qv[f] * w2a[2][f];
            o.w += qv[f] * w2a[3][f];
        }
        __builtin_nontemporal_store(o, (f4*)(out + (size_t)(row0 + s) * E + c0));
    }
}

extern "C" void kernel_launch(void* const* d_in, const int* in_sizes, int n_in,
                              void* d_out, int out_size, void* d_ws, size_t ws_size,
                              hipStream_t stream)
{
    const float* x  = (const float*)d_in[0];
    const float* w1 = (const float*)d_in[1];
    const float* b1 = (const float*)d_in[2];
    const float* w2 = (const float*)d_in[3];
    const float* b2 = (const float*)d_in[4];
    float* out = (float*)d_out;

    ffq_kernel<<<dim3(R_TOTAL / TILE), THREADS, 0, stream>>>(x, w1, b1, w2, b2, out);
}